// Round 15
// baseline (282.915 us; speedup 1.0000x reference)
//
#include <hip/hip_runtime.h>
#include <hip/hip_bf16.h>

#define N_ 8192
#define I_ 1024
#define O_ 1024
#define P_ 8
#define C_ 64
#define OP_ (O_ * P_)

typedef float f32x4 __attribute__((ext_vector_type(4)));
typedef __bf16 bf16x8 __attribute__((ext_vector_type(8)));
typedef unsigned short ushort8 __attribute__((ext_vector_type(8)));

#define GLOBAL_AS(p) ((const __attribute__((address_space(1))) unsigned int*)(p))
#define LDS_AS(p) ((__attribute__((address_space(3))) unsigned int*)(p))

// ---------------------------------------------------------------------------
// Kernel P: fused prep. Blocks 0-255: split protos -> ph,pl. 256-511: split
// ctx -> ch,cl. 512-543: psq (fp32 exact, sequential-c order).
// ---------------------------------------------------------------------------
__global__ __launch_bounds__(256)
void prep_kernel(const float* __restrict__ protos, const float* __restrict__ ctx,
                 unsigned short* __restrict__ ph, unsigned short* __restrict__ pl,
                 unsigned short* __restrict__ ch, unsigned short* __restrict__ cl,
                 float* __restrict__ psq) {
    const int b = blockIdx.x;
    if (b < 512) {
        const float* src = (b < 256) ? protos : ctx;
        unsigned short* hi = (b < 256) ? ph : ch;
        unsigned short* lo = (b < 256) ? pl : cl;
        const int idx = (b & 255) * 256 + threadIdx.x;
        const float* sp = src + (size_t)idx * 8;
        const float4 f0 = *(const float4*)(sp);
        const float4 f1 = *(const float4*)(sp + 4);
        float f[8] = {f0.x, f0.y, f0.z, f0.w, f1.x, f1.y, f1.z, f1.w};
        ushort8 vh, vl;
        #pragma unroll
        for (int e = 0; e < 8; ++e) {
            const __hip_bfloat16 h = __float2bfloat16(f[e]);
            const __hip_bfloat16 l = __float2bfloat16(f[e] - __bfloat162float(h));
            vh[e] = __builtin_bit_cast(unsigned short, h);
            vl[e] = __builtin_bit_cast(unsigned short, l);
        }
        *(ushort8*)(hi + (size_t)idx * 8) = vh;
        *(ushort8*)(lo + (size_t)idx * 8) = vl;
    } else {
        const int idx = (b - 512) * 256 + threadIdx.x;  // 0..8191
        const float* pr = protos + (size_t)idx * C_;
        float s = 0.f;
        #pragma unroll
        for (int c = 0; c < C_; ++c) s = fmaf(pr[c], pr[c], s);
        psq[idx] = s;
    }
}

// ---------------------------------------------------------------------------
// Kernel M: MEGA — converts + argmin interleaved (validated r13/r14).
//   bid%3==2 -> argmin block (flag thr 4e-3)
//   else     -> convert block, writing the r5/r6 ROWPAIR layout:
//     chunk idx = rp*256 + t*8 + j (rp=row>>1, t=K-tile of 32, j=0..7)
//     holds octet c = j ^ (rp&7): row = 2rp + (c>>2), k0 = t*32 + (c&3)*8
// ---------------------------------------------------------------------------
__global__ __launch_bounds__(256, 2)
void mega_kernel(const float* __restrict__ X, const float* __restrict__ W,
                 unsigned short* __restrict__ Xb, unsigned short* __restrict__ Wb,
                 const unsigned short* __restrict__ ph, const unsigned short* __restrict__ pl,
                 const unsigned short* __restrict__ ch, const unsigned short* __restrict__ cl,
                 const float* __restrict__ psq, unsigned char* __restrict__ best) {
    const int bid = blockIdx.x;
    const int tid = threadIdx.x;

    if (bid % 3 != 2) {
        // ---------------- convert role (r5/r6 rowpair mapping) --------------
        const int cidx = bid - (bid + 1) / 3;        // 0..8191
        const int side = cidx >> 12;
        const float* src = side ? W : X;
        unsigned short* dst = side ? Wb : Xb;
        const int idx = (cidx & 4095) * 256 + tid;   // 1,048,576 chunks
        const int rp = idx >> 8;
        const int t = (idx >> 3) & 31;
        const int j = idx & 7;
        const int c = j ^ (rp & 7);
        const int row = rp * 2 + (c >> 2);
        const int k0 = t * 32 + (c & 3) * 8;
        const float* sp = src + (size_t)row * I_ + k0;
        const float4 f0 = *(const float4*)(sp);
        const float4 f1 = *(const float4*)(sp + 4);
        const float f[8] = {f0.x, f0.y, f0.z, f0.w, f1.x, f1.y, f1.z, f1.w};
        ushort8 v;
        #pragma unroll
        for (int e = 0; e < 8; ++e)
            v[e] = __builtin_bit_cast(unsigned short, __float2bfloat16(f[e]));
        *(ushort8*)(dst + (size_t)idx * 8) = v;
        return;
    }

    // ---------------- argmin role (validated r10-r14) ----------------
    const int aidx = bid / 3;                        // 0..4095
    const int w = tid >> 6, l = tid & 63;
    const int op0 = (aidx & 63) * 128;
    const int nw = (aidx >> 6) * 128 + w * 32;
    const int lr = l & 15, lk = l >> 4;

    f32x4 acc[8][2];
    #pragma unroll
    for (int of = 0; of < 8; ++of)
        #pragma unroll
        for (int nf = 0; nf < 2; ++nf) acc[of][nf] = (f32x4)(0.f);

    #pragma unroll
    for (int ks = 0; ks < 2; ++ks) {
        const int ko = ks * 32 + lk * 8;
        bf16x8 Ah[8], Al[8], Bh[2], Bl[2];
        #pragma unroll
        for (int of = 0; of < 8; ++of) {
            const size_t r = (size_t)(op0 + of * 16 + lr) * C_ + ko;
            Ah[of] = *(const bf16x8*)(ph + r);
            Al[of] = *(const bf16x8*)(pl + r);
        }
        #pragma unroll
        for (int nf = 0; nf < 2; ++nf) {
            const size_t r = (size_t)(nw + nf * 16 + lr) * C_ + ko;
            Bh[nf] = *(const bf16x8*)(ch + r);
            Bl[nf] = *(const bf16x8*)(cl + r);
        }
        #pragma unroll
        for (int of = 0; of < 8; ++of)
            #pragma unroll
            for (int nf = 0; nf < 2; ++nf) {
                acc[of][nf] = __builtin_amdgcn_mfma_f32_16x16x32_bf16(Ah[of], Bh[nf], acc[of][nf], 0, 0, 0);
                acc[of][nf] = __builtin_amdgcn_mfma_f32_16x16x32_bf16(Ah[of], Bl[nf], acc[of][nf], 0, 0, 0);
                acc[of][nf] = __builtin_amdgcn_mfma_f32_16x16x32_bf16(Al[of], Bh[nf], acc[of][nf], 0, 0, 0);
            }
    }

    #pragma unroll
    for (int of = 0; of < 8; ++of) {
        const int oprow0 = op0 + of * 16;
        const f32x4 ps = *(const f32x4*)(psq + oprow0 + lk * 4);
        #pragma unroll
        for (int nf = 0; nf < 2; ++nf) {
            const float d0 = fmaf(-2.f, acc[of][nf][0], ps[0]);
            const float d1 = fmaf(-2.f, acc[of][nf][1], ps[1]);
            const float d2 = fmaf(-2.f, acc[of][nf][2], ps[2]);
            const float d3 = fmaf(-2.f, acc[of][nf][3], ps[3]);
            const float e0 = __shfl_xor(d0, 16, 64);
            const float e1 = __shfl_xor(d1, 16, 64);
            const float e2 = __shfl_xor(d2, 16, 64);
            const float e3 = __shfl_xor(d3, 16, 64);
            float b1v = 3.4e38f, b2v = 3.4e38f;
            int bi = 0;
            #define UPD(val, pidx) do { const float _f = (val);                       \
                if (_f < b1v) { b2v = b1v; b1v = _f; bi = (pidx); }                   \
                else if (_f < b2v) b2v = _f; } while (0)
            UPD(d0, 0); UPD(d1, 1); UPD(d2, 2); UPD(d3, 3);
            UPD(e0, 4); UPD(e1, 5); UPD(e2, 6); UPD(e3, 7);
            #undef UPD
            if ((lk & 1) == 0) {
                const int o = (oprow0 >> 3) + (lk >> 1);
                const int n = nw + nf * 16 + lr;
                const unsigned flag = (b2v - b1v < 4e-3f) ? 0x80u : 0u;
                best[(size_t)o * N_ + n] = (unsigned char)((unsigned)bi | flag);
            }
        }
    }
}

// ---------------------------------------------------------------------------
// Kernel F: block-local fixup (validated r14). LDS queue, 8 lanes/elem fp64,
// ascending-p first-min; clears flag bits.
// ---------------------------------------------------------------------------
__global__ __launch_bounds__(256)
void fixup_kernel(const float* __restrict__ ctx, const float* __restrict__ protos,
                  unsigned char* __restrict__ best) {
    __shared__ unsigned q[8192];
    __shared__ unsigned qcnt;
    const int tid = threadIdx.x;
    if (tid == 0) qcnt = 0;
    __syncthreads();

    const size_t base = (size_t)blockIdx.x * 8192;
    const uint4* bw4 = (const uint4*)(best + base);
    #pragma unroll
    for (int i = 0; i < 2; ++i) {
        const uint4 v = bw4[tid * 2 + i];
        const unsigned wds[4] = {v.x, v.y, v.z, v.w};
        #pragma unroll
        for (int wq = 0; wq < 4; ++wq) {
            unsigned fl = wds[wq] & 0x80808080u;
            while (fl) {
                const int bq = __builtin_ctz(fl) >> 3;
                fl &= fl - 1;
                const unsigned slot = atomicAdd(&qcnt, 1u);
                q[slot] = (unsigned)(tid * 32 + i * 16 + wq * 4 + bq);
            }
        }
    }
    __syncthreads();

    const unsigned cnt = qcnt;
    const int lane8 = tid & 7;
    for (unsigned e = (unsigned)(tid >> 3); e < cnt; e += 32) {
        const size_t off = base + q[e];
        const int n = (int)(off & (N_ - 1));
        const int o = (int)(off >> 13);
        const float* cr = ctx + (size_t)n * C_;
        const float* pr = protos + ((size_t)o * 8 + lane8) * C_;
        double s = 0.0;
        #pragma unroll 8
        for (int c = 0; c < C_; ++c) {
            const double pv = (double)pr[c];
            const double cv = (double)cr[c];
            s += pv * (pv - 2.0 * cv);
        }
        int bi = lane8;
        #pragma unroll
        for (int d = 1; d < 8; d <<= 1) {
            const double s2 = __shfl_xor(s, d, 64);
            const int b2 = __shfl_xor(bi, d, 64);
            if (s2 < s || (s2 == s && b2 < bi)) { s = s2; bi = b2; }
        }
        if (lane8 == 0) best[off] = (unsigned char)bi;
    }
}

// ---------------------------------------------------------------------------
// Kernel B: BK=32 double-buffered bf16 MFMA GEMM (r6 structure, FIXED
// launch bounds). 64 KiB LDS -> 2 blocks/CU; cross-block TLP fills the
// per-tile drain stall. 1 barrier + 1 vmcnt(0) per tile, 32 tiles.
// Fused argmin-gather epilogue (u32 best loads).
// ---------------------------------------------------------------------------
__global__ __launch_bounds__(512)
void gemm_gather_kernel(const unsigned short* __restrict__ Xb,
                        const unsigned short* __restrict__ Wb,
                        const float* __restrict__ bias,
                        const unsigned char* __restrict__ best,
                        float* __restrict__ out) {
    extern __shared__ unsigned short lds[];  // 2 x (A 16KB + B 16KB) = 64 KiB

    int wg = blockIdx.x;                     // 1024 blocks, %8==0 -> bijective
    wg = (wg & 7) * 128 + (wg >> 3);
    const int bx = wg & 31;
    const int by = wg >> 5;
    const int n0 = by * 256;
    const int col0 = bx * 256;

    const int tid = threadIdx.x;
    const int w = tid >> 6, l = tid & 63;
    const int wr = w >> 2, wc = w & 3;
    const int lr = l & 15, lk = l >> 4;

    const int rpgA = n0 >> 1;
    const int rpgB = col0 >> 1;

    #define STAGE(gsrc, rpg0, tt, ldsbase) do {                                     \
        _Pragma("unroll")                                                           \
        for (int _ld = 0; _ld < 2; ++_ld) {                                         \
            const int _L = _ld * 512 + tid;                                         \
            __builtin_amdgcn_global_load_lds(                                       \
                GLOBAL_AS((gsrc) + (((size_t)((rpg0) + (_L >> 3)) * 256 +           \
                                     (size_t)(tt) * 8 + (_L & 7)) * 8)),            \
                LDS_AS((ldsbase) + _L * 8), 16, 0, 0);                              \
        }                                                                           \
    } while (0)

    #define VMCNT0() do { asm volatile("s_waitcnt vmcnt(0)" ::: "memory");          \
        __builtin_amdgcn_sched_barrier(0); } while (0)
    #define BAR() __builtin_amdgcn_s_barrier()

    f32x4 acc[8][4];
    #pragma unroll
    for (int m = 0; m < 8; ++m)
        #pragma unroll
        for (int n = 0; n < 4; ++n) acc[m][n] = (f32x4)(0.f);

    bf16x8 af0[4], af1[4], bf[4];

    #define RD_A(dst, mbase, bb) do {                                                \
        _Pragma("unroll")                                                            \
        for (int _m = 0; _m < 4; ++_m) {                                             \
            const int _R = wr * 128 + ((mbase) + _m) * 16 + lr;                      \
            const int _rp = _R >> 1;                                                 \
            const int _j = (((_R & 1) << 2) + lk) ^ (_rp & 7);                       \
            dst[_m] = *(const bf16x8*)&lds[(bb) * 16384 + _rp * 64 + _j * 8];        \
        }                                                                            \
    } while (0)

    #define RD_B(bb) do {                                                            \
        _Pragma("unroll")                                                            \
        for (int _n = 0; _n < 4; ++_n) {                                             \
            const int _R = wc * 64 + _n * 16 + lr;                                   \
            const int _rp = _R >> 1;                                                 \
            const int _j = (((_R & 1) << 2) + lk) ^ (_rp & 7);                       \
            bf[_n] = *(const bf16x8*)&lds[(bb) * 16384 + 8192 + _rp * 64 + _j * 8];  \
        }                                                                            \
    } while (0)

    #define MFMA16(src, mbase) do {                                                  \
        __builtin_amdgcn_s_setprio(1);                                               \
        _Pragma("unroll")                                                            \
        for (int _m = 0; _m < 4; ++_m)                                               \
            _Pragma("unroll")                                                        \
            for (int _n = 0; _n < 4; ++_n)                                           \
                acc[(mbase) + _m][_n] =                                              \
                    __builtin_amdgcn_mfma_f32_16x16x32_bf16(                         \
                        src[_m], bf[_n], acc[(mbase) + _m][_n], 0, 0, 0);            \
        __builtin_amdgcn_s_setprio(0);                                               \
    } while (0)

    // ---- prologue: stage tile 0 into buf0; drain ----
    STAGE(Xb, rpgA, 0, lds);
    STAGE(Wb, rpgB, 0, lds + 8192);
    VMCNT0();
    BAR();

    #pragma unroll 2
    for (int t = 0; t < 32; ++t) {
        const int b = t & 1;
        const int nb = b ^ 1;
        if (t + 1 < 32) {
            STAGE(Xb, rpgA, t + 1, lds + nb * 16384);
            STAGE(Wb, rpgB, t + 1, lds + nb * 16384 + 8192);
        }
        RD_A(af0, 0, b);
        RD_B(b);
        RD_A(af1, 4, b);
        MFMA16(af0, 0);
        MFMA16(af1, 4);
        VMCNT0();
        BAR();
    }

    // ---- epilogue: fused argmin-gather + bias; u32 best loads ----
    const int nbase = n0 + wr * 128 + lk * 4;
    #pragma unroll
    for (int nf = 0; nf < 4; ++nf) {
        const int opcol = col0 + wc * 64 + nf * 16 + lr;
        const int o = opcol >> 3;
        const unsigned p = (unsigned)(opcol & 7);
        const float bv = bias[opcol];
        const unsigned char* brow = best + (size_t)o * N_ + nbase;
        #pragma unroll
        for (int m = 0; m < 8; ++m) {
            const unsigned b4 = *(const unsigned*)(brow + m * 16);
            #pragma unroll
            for (int j = 0; j < 4; ++j) {
                if (((b4 >> (j * 8)) & 255u) == p) {
                    const int n = nbase + m * 16 + j;
                    out[(size_t)n * O_ + o] = acc[m][nf][j] + bv;
                }
            }
        }
    }
    #undef STAGE
    #undef RD_A
    #undef RD_B
    #undef MFMA16
    #undef VMCNT0
    #undef BAR
}

// ---------------------------------------------------------------------------
extern "C" void kernel_launch(void* const* d_in, const int* in_sizes, int n_in,
                              void* d_out, int out_size, void* d_ws, size_t ws_size,
                              hipStream_t stream) {
    const float* X      = (const float*)d_in[0];
    const float* ctx    = (const float*)d_in[1];
    const float* W      = (const float*)d_in[2];
    const float* bias   = (const float*)d_in[3];
    const float* protos = (const float*)d_in[4];
    float* out = (float*)d_out;

    char* ws = (char*)d_ws;
    unsigned char* best = (unsigned char*)ws;                         // 8 MiB
    float* psq = (float*)(ws + ((size_t)8 << 20));                    // 32 KiB
    unsigned short* Xb = (unsigned short*)(ws + ((size_t)9 << 20));   // 16 MiB
    unsigned short* Wb = (unsigned short*)(ws + ((size_t)25 << 20));  // 16 MiB

    // split-bf16 scratch lives in d_out (fully overwritten by gemm later)
    char* ob = (char*)d_out;
    unsigned short* ph = (unsigned short*)(ob + ((size_t)16 << 20));  // 1 MiB
    unsigned short* pl = (unsigned short*)(ob + ((size_t)17 << 20));  // 1 MiB
    unsigned short* ch = (unsigned short*)(ob + ((size_t)18 << 20));  // 1 MiB
    unsigned short* cl = (unsigned short*)(ob + ((size_t)19 << 20));  // 1 MiB

    hipFuncSetAttribute((const void*)gemm_gather_kernel,
                        hipFuncAttributeMaxDynamicSharedMemorySize, 65536);

    prep_kernel<<<dim3(544), dim3(256), 0, stream>>>(protos, ctx, ph, pl, ch, cl, psq);
    mega_kernel<<<dim3(12288), dim3(256), 0, stream>>>(X, W, Xb, Wb, ph, pl, ch, cl, psq, best);
    fixup_kernel<<<dim3(1024), dim3(256), 0, stream>>>(ctx, protos, best);
    gemm_gather_kernel<<<dim3(1024), dim3(512), 65536, stream>>>(Xb, Wb, bias, best, out);
}

// Round 16
// 263.721 us; speedup vs baseline: 1.0728x; 1.0728x over previous
//
#include <hip/hip_runtime.h>
#include <hip/hip_bf16.h>

#define N_ 8192
#define I_ 1024
#define O_ 1024
#define P_ 8
#define C_ 64
#define OP_ (O_ * P_)

typedef float f32x4 __attribute__((ext_vector_type(4)));
typedef __bf16 bf16x8 __attribute__((ext_vector_type(8)));
typedef unsigned short ushort8 __attribute__((ext_vector_type(8)));

#define GLOBAL_AS(p) ((const __attribute__((address_space(1))) unsigned int*)(p))
#define LDS_AS(p) ((__attribute__((address_space(3))) unsigned int*)(p))

// ---------------------------------------------------------------------------
// Kernel M: MEGA — converts + argmin interleaved (validated r13/r14), now
// with NO prep dependency: argmin loads fp32 protos/ctx (same bytes as the
// old split pair), splits hi/lo in-register, and computes psq in-register
// (2 shfl_xor reduce over lk-groups + 4 shfl redistribute). Flag thr 4e-3
// absorbs the psq reorder error (~2e-5 << 2.4e-3 split bound).
//   bid%3==2 -> argmin block ; else -> convert block (r14 layouts).
// ---------------------------------------------------------------------------
__global__ __launch_bounds__(256, 2)
void mega_kernel(const float* __restrict__ X, const float* __restrict__ W,
                 unsigned short* __restrict__ Xb, unsigned short* __restrict__ Wb,
                 const float* __restrict__ ctx, const float* __restrict__ protos,
                 unsigned char* __restrict__ best) {
    const int bid = blockIdx.x;
    const int tid = threadIdx.x;

    if (bid % 3 != 2) {
        // ---------------- convert role (r14 half-tile layouts) --------------
        const int cidx = bid - (bid + 1) / 3;        // 0..8191
        const int side = cidx >> 12;                 // 0: X (layout A), 1: W (layout B)
        const float* src = side ? W : X;
        unsigned short* dst = side ? Wb : Xb;
        const int idx = (cidx & 4095) * 256 + tid;   // 1,048,576 chunks
        const int rb = idx >> 15;
        const int r = idx & 32767;
        const int kt = r >> 11;
        const int h = (r >> 10) & 1;
        const int L = r & 1023;
        const int Lr = L >> 3;
        const int j = L & 7;
        const int c = j ^ (Lr & 7);
        int Rl;
        if (side == 0) Rl = (Lr & 63) + ((Lr & 64) << 1) + h * 64;
        else           Rl = ((Lr >> 5) << 6) + h * 32 + (Lr & 31);
        const float* sp = src + (size_t)(rb * 256 + Rl) * I_ + kt * 64 + c * 8;
        const float4 f0 = *(const float4*)(sp);
        const float4 f1 = *(const float4*)(sp + 4);
        const float f[8] = {f0.x, f0.y, f0.z, f0.w, f1.x, f1.y, f1.z, f1.w};
        ushort8 v;
        #pragma unroll
        for (int e = 0; e < 8; ++e)
            v[e] = __builtin_bit_cast(unsigned short, __float2bfloat16(f[e]));
        *(ushort8*)(dst + (size_t)idx * 8) = v;
        return;
    }

    // ---------------- argmin role (fp32 loads + in-register split) ----------
    const int aidx = bid / 3;                        // 0..4095
    const int w = tid >> 6, l = tid & 63;
    const int op0 = (aidx & 63) * 128;
    const int nw = (aidx >> 6) * 128 + w * 32;
    const int lr = l & 15, lk = l >> 4;

    f32x4 acc[8][2];
    #pragma unroll
    for (int of = 0; of < 8; ++of)
        #pragma unroll
        for (int nf = 0; nf < 2; ++nf) acc[of][nf] = (f32x4)(0.f);

    float psqp[8];
    #pragma unroll
    for (int of = 0; of < 8; ++of) psqp[of] = 0.f;

    #pragma unroll
    for (int ks = 0; ks < 2; ++ks) {
        const int ko = ks * 32 + lk * 8;
        bf16x8 Ah[8], Al[8], Bh[2], Bl[2];
        #pragma unroll
        for (int of = 0; of < 8; ++of) {
            const float* pr = protos + (size_t)(op0 + of * 16 + lr) * C_ + ko;
            const float4 a0 = *(const float4*)(pr);
            const float4 a1 = *(const float4*)(pr + 4);
            const float fa[8] = {a0.x, a0.y, a0.z, a0.w, a1.x, a1.y, a1.z, a1.w};
            #pragma unroll
            for (int e = 0; e < 8; ++e) {
                const float f = fa[e];
                const __hip_bfloat16 hh = __float2bfloat16(f);
                Ah[of][e] = __builtin_bit_cast(__bf16, __builtin_bit_cast(unsigned short, hh));
                const __hip_bfloat16 ll = __float2bfloat16(f - __bfloat162float(hh));
                Al[of][e] = __builtin_bit_cast(__bf16, __builtin_bit_cast(unsigned short, ll));
                psqp[of] = fmaf(f, f, psqp[of]);
            }
        }
        #pragma unroll
        for (int nf = 0; nf < 2; ++nf) {
            const float* cr = ctx + (size_t)(nw + nf * 16 + lr) * C_ + ko;
            const float4 b0 = *(const float4*)(cr);
            const float4 b1 = *(const float4*)(cr + 4);
            const float fb[8] = {b0.x, b0.y, b0.z, b0.w, b1.x, b1.y, b1.z, b1.w};
            #pragma unroll
            for (int e = 0; e < 8; ++e) {
                const float f = fb[e];
                const __hip_bfloat16 hh = __float2bfloat16(f);
                Bh[nf][e] = __builtin_bit_cast(__bf16, __builtin_bit_cast(unsigned short, hh));
                const __hip_bfloat16 ll = __float2bfloat16(f - __bfloat162float(hh));
                Bl[nf][e] = __builtin_bit_cast(__bf16, __builtin_bit_cast(unsigned short, ll));
            }
        }
        #pragma unroll
        for (int of = 0; of < 8; ++of)
            #pragma unroll
            for (int nf = 0; nf < 2; ++nf) {
                acc[of][nf] = __builtin_amdgcn_mfma_f32_16x16x32_bf16(Ah[of], Bh[nf], acc[of][nf], 0, 0, 0);
                acc[of][nf] = __builtin_amdgcn_mfma_f32_16x16x32_bf16(Ah[of], Bl[nf], acc[of][nf], 0, 0, 0);
                acc[of][nf] = __builtin_amdgcn_mfma_f32_16x16x32_bf16(Al[of], Bh[nf], acc[of][nf], 0, 0, 0);
            }
    }

    // full-row psq: reduce partial over the 4 lk-groups (same lr)
    float psqf[8];
    #pragma unroll
    for (int of = 0; of < 8; ++of) {
        float s = psqp[of];
        s += __shfl_xor(s, 16, 64);
        s += __shfl_xor(s, 32, 64);
        psqf[of] = s;   // psq of row op0 + of*16 + lr
    }

    #pragma unroll
    for (int of = 0; of < 8; ++of) {
        const int oprow0 = op0 + of * 16;
        // redistribute: lane needs rows lk*4+j; source lanes 0..15 hold lr=lane
        float ps[4];
        #pragma unroll
        for (int j = 0; j < 4; ++j) ps[j] = __shfl(psqf[of], lk * 4 + j, 64);
        #pragma unroll
        for (int nf = 0; nf < 2; ++nf) {
            const float d0 = fmaf(-2.f, acc[of][nf][0], ps[0]);
            const float d1 = fmaf(-2.f, acc[of][nf][1], ps[1]);
            const float d2 = fmaf(-2.f, acc[of][nf][2], ps[2]);
            const float d3 = fmaf(-2.f, acc[of][nf][3], ps[3]);
            const float e0 = __shfl_xor(d0, 16, 64);
            const float e1 = __shfl_xor(d1, 16, 64);
            const float e2 = __shfl_xor(d2, 16, 64);
            const float e3 = __shfl_xor(d3, 16, 64);
            float b1v = 3.4e38f, b2v = 3.4e38f;
            int bi = 0;
            #define UPD(val, pidx) do { const float _f = (val);                       \
                if (_f < b1v) { b2v = b1v; b1v = _f; bi = (pidx); }                   \
                else if (_f < b2v) b2v = _f; } while (0)
            UPD(d0, 0); UPD(d1, 1); UPD(d2, 2); UPD(d3, 3);
            UPD(e0, 4); UPD(e1, 5); UPD(e2, 6); UPD(e3, 7);
            #undef UPD
            if ((lk & 1) == 0) {
                const int o = (oprow0 >> 3) + (lk >> 1);
                const int n = nw + nf * 16 + lr;
                const unsigned flag = (b2v - b1v < 4e-3f) ? 0x80u : 0u;
                best[(size_t)o * N_ + n] = (unsigned char)((unsigned)bi | flag);
            }
        }
    }
}

// ---------------------------------------------------------------------------
// Kernel F: block-local fixup (validated r14). LDS queue, 8 lanes/elem fp64,
// ascending-p first-min; clears flag bits.
// ---------------------------------------------------------------------------
__global__ __launch_bounds__(256)
void fixup_kernel(const float* __restrict__ ctx, const float* __restrict__ protos,
                  unsigned char* __restrict__ best) {
    __shared__ unsigned q[8192];
    __shared__ unsigned qcnt;
    const int tid = threadIdx.x;
    if (tid == 0) qcnt = 0;
    __syncthreads();

    const size_t base = (size_t)blockIdx.x * 8192;
    const uint4* bw4 = (const uint4*)(best + base);
    #pragma unroll
    for (int i = 0; i < 2; ++i) {
        const uint4 v = bw4[tid * 2 + i];
        const unsigned wds[4] = {v.x, v.y, v.z, v.w};
        #pragma unroll
        for (int wq = 0; wq < 4; ++wq) {
            unsigned fl = wds[wq] & 0x80808080u;
            while (fl) {
                const int bq = __builtin_ctz(fl) >> 3;
                fl &= fl - 1;
                const unsigned slot = atomicAdd(&qcnt, 1u);
                q[slot] = (unsigned)(tid * 32 + i * 16 + wq * 4 + bq);
            }
        }
    }
    __syncthreads();

    const unsigned cnt = qcnt;
    const int lane8 = tid & 7;
    for (unsigned e = (unsigned)(tid >> 3); e < cnt; e += 32) {
        const size_t off = base + q[e];
        const int n = (int)(off & (N_ - 1));
        const int o = (int)(off >> 13);
        const float* cr = ctx + (size_t)n * C_;
        const float* pr = protos + ((size_t)o * 8 + lane8) * C_;
        double s = 0.0;
        #pragma unroll 8
        for (int c = 0; c < C_; ++c) {
            const double pv = (double)pr[c];
            const double cv = (double)cr[c];
            s += pv * (pv - 2.0 * cv);
        }
        int bi = lane8;
        #pragma unroll
        for (int d = 1; d < 8; d <<= 1) {
            const double s2 = __shfl_xor(s, d, 64);
            const int b2 = __shfl_xor(bi, d, 64);
            if (s2 < s || (s2 == s && b2 < bi)) { s = s2; bi = b2; }
        }
        if (lane8 == 0) best[off] = (unsigned char)bi;
    }
}

// ---------------------------------------------------------------------------
// Kernel B: 256x256 phase-pipelined bf16 MFMA GEMM — r14 VERBATIM (151us):
// r10 schedule (vmcnt(4) each phase, 1 barrier/phase), no explicit lgkmcnt
// drains (compiler emits fine-grained lgkmcnt). Fused argmin-gather epilogue.
// ---------------------------------------------------------------------------
__global__ __launch_bounds__(512, 1)
void gemm_gather_kernel(const unsigned short* __restrict__ Xb,
                        const unsigned short* __restrict__ Wb,
                        const float* __restrict__ bias,
                        const unsigned char* __restrict__ best,
                        float* __restrict__ out) {
    extern __shared__ unsigned short lds[];  // 2 x (A 16384 + B 16384) ushort = 128 KiB

    int wg = blockIdx.x;                     // 1024 blocks, %8==0 -> bijective
    wg = (wg & 7) * 128 + (wg >> 3);
    const int bx = wg & 31;
    const int by = wg >> 5;
    const int n0 = by * 256;
    const int col0 = bx * 256;

    const int tid = threadIdx.x;
    const int w = tid >> 6, l = tid & 63;
    const int wr = w >> 2, wc = w & 3;
    const int lr = l & 15, lk = l >> 4;
    const int lx = lr & 7;

    const unsigned short* Xrb = Xb + (size_t)(n0 >> 8) * 262144;
    const unsigned short* Wrb = Wb + (size_t)(col0 >> 8) * 262144;

    #define STAGE(src, ktt, h, ldsofs) do {                                          \
        const unsigned short* _g = (src) + ((size_t)(ktt) * 2 + (h)) * 8192;         \
        __builtin_amdgcn_global_load_lds(GLOBAL_AS(_g + (size_t)tid * 8),            \
            LDS_AS(lds + (ldsofs) + tid * 8), 16, 0, 0);                             \
        __builtin_amdgcn_global_load_lds(GLOBAL_AS(_g + (size_t)(tid + 512) * 8),    \
            LDS_AS(lds + (ldsofs) + (tid + 512) * 8), 16, 0, 0);                     \
    } while (0)

    #define VMCNT4() do { asm volatile("s_waitcnt vmcnt(4)" ::: "memory");           \
        __builtin_amdgcn_sched_barrier(0); } while (0)
    #define VMCNT2() do { asm volatile("s_waitcnt vmcnt(2)" ::: "memory");           \
        __builtin_amdgcn_sched_barrier(0); } while (0)
    #define VMCNT0() do { asm volatile("s_waitcnt vmcnt(0)" ::: "memory");           \
        __builtin_amdgcn_sched_barrier(0); } while (0)
    #define BAR() __builtin_amdgcn_s_barrier()

    f32x4 acc[8][4];
    #pragma unroll
    for (int m = 0; m < 8; ++m)
        #pragma unroll
        for (int n = 0; n < 4; ++n) acc[m][n] = (f32x4)(0.f);

    #define RD_A(dst, mbase, bb) do {                                                \
        _Pragma("unroll")                                                            \
        for (int _m = 0; _m < 4; ++_m) {                                             \
            const int _R = wr * 128 + ((mbase) + _m) * 16 + lr;                      \
            const int _h = (_R >> 6) & 1;                                            \
            const int _Lr = (_R & 63) + ((_R & 128) >> 1);                           \
            _Pragma("unroll")                                                        \
            for (int _k = 0; _k < 2; ++_k) {                                         \
                const int _s = (_k * 4 + lk) ^ lx;                                   \
                dst[_m][_k] = *(const bf16x8*)&lds[(bb) * 32768 + _h * 8192 +        \
                                                   _Lr * 64 + _s * 8];               \
            }                                                                        \
        }                                                                            \
    } while (0)

    #define RD_B(dst, nbase, bb) do {                                                \
        _Pragma("unroll")                                                            \
        for (int _n = 0; _n < 2; ++_n) {                                             \
            const int _R = wc * 64 + ((nbase) + _n) * 16 + lr;                       \
            const int _h = (_R >> 5) & 1;                                            \
            const int _Lr = ((_R >> 6) << 5) + (_R & 31);                            \
            _Pragma("unroll")                                                        \
            for (int _k = 0; _k < 2; ++_k) {                                         \
                const int _s = (_k * 4 + lk) ^ lx;                                   \
                dst[_n][_k] = *(const bf16x8*)&lds[(bb) * 32768 + 16384 +            \
                                                   _h * 8192 + _Lr * 64 + _s * 8];   \
            }                                                                        \
        }                                                                            \
    } while (0)

    #define MFMA16(AF, BF, MB, NB) do {                                              \
        __builtin_amdgcn_s_setprio(1);                                               \
        _Pragma("unroll")                                                            \
        for (int _m = 0; _m < 4; ++_m)                                               \
            _Pragma("unroll")                                                        \
            for (int _n = 0; _n < 2; ++_n)                                           \
                _Pragma("unroll")                                                    \
                for (int _k = 0; _k < 2; ++_k)                                       \
                    acc[(MB) + _m][(NB) + _n] =                                      \
                        __builtin_amdgcn_mfma_f32_16x16x32_bf16(                     \
                            AF[_m][_k], BF[_n][_k], acc[(MB) + _m][(NB) + _n], 0, 0, 0); \
        __builtin_amdgcn_s_setprio(0);                                               \
    } while (0)

    bf16x8 af[4][2], bfa[2][2], bfb[2][2];

    // ---- prologue: stage kt0 {Aa,Ba,Bb,Ab}; drain Aa0,Ba0 ----
    STAGE(Xrb, 0, 0, 0);
    STAGE(Wrb, 0, 0, 16384);
    STAGE(Wrb, 0, 1, 16384 + 8192);
    STAGE(Xrb, 0, 1, 8192);
    VMCNT4();
    BAR();

    #pragma unroll 1
    for (int kt = 0; kt < 15; ++kt) {
        const int b = kt & 1, nb = b ^ 1;
        const int nbo = nb * 32768;
        RD_A(af, 0, b);
        RD_B(bfa, 0, b);
        STAGE(Wrb, kt + 1, 0, nbo + 16384);
        VMCNT4();
        BAR();
        MFMA16(af, bfa, 0, 0);
        RD_B(bfb, 2, b);
        STAGE(Xrb, kt + 1, 0, nbo);
        VMCNT4();
        BAR();
        MFMA16(af, bfb, 0, 2);
        RD_A(af, 4, b);
        STAGE(Wrb, kt + 1, 1, nbo + 16384 + 8192);
        VMCNT4();
        BAR();
        MFMA16(af, bfb, 4, 2);
        RD_B(bfa, 0, b);
        STAGE(Xrb, kt + 1, 1, nbo + 8192);
        VMCNT4();
        BAR();
        MFMA16(af, bfa, 4, 0);
    }
    {   // tail kt=15 (buf 1, no staging)
        RD_A(af, 0, 1);
        RD_B(bfa, 0, 1);
        VMCNT2();
        BAR();
        MFMA16(af, bfa, 0, 0);
        RD_B(bfb, 2, 1);
        VMCNT0();
        BAR();
        MFMA16(af, bfb, 0, 2);
        RD_A(af, 4, 1);
        MFMA16(af, bfb, 4, 2);
        RD_B(bfa, 0, 1);
        MFMA16(af, bfa, 4, 0);
    }

    // ---- epilogue: fused argmin-gather + bias; u32 best loads ----
    const int nbase = n0 + wr * 128 + lk * 4;
    #pragma unroll
    for (int nf = 0; nf < 4; ++nf) {
        const int opcol = col0 + wc * 64 + nf * 16 + lr;
        const int o = opcol >> 3;
        const unsigned p = (unsigned)(opcol & 7);
        const float bv = bias[opcol];
        const unsigned char* brow = best + (size_t)o * N_ + nbase;
        #pragma unroll
        for (int m = 0; m < 8; ++m) {
            const unsigned b4 = *(const unsigned*)(brow + m * 16);
            #pragma unroll
            for (int j = 0; j < 4; ++j) {
                if (((b4 >> (j * 8)) & 255u) == p) {
                    const int n = nbase + m * 16 + j;
                    out[(size_t)n * O_ + o] = acc[m][nf][j] + bv;
                }
            }
        }
    }
    #undef STAGE
    #undef RD_A
    #undef RD_B
    #undef MFMA16
    #undef VMCNT4
    #undef VMCNT2
    #undef VMCNT0
    #undef BAR
}

// ---------------------------------------------------------------------------
extern "C" void kernel_launch(void* const* d_in, const int* in_sizes, int n_in,
                              void* d_out, int out_size, void* d_ws, size_t ws_size,
                              hipStream_t stream) {
    const float* X      = (const float*)d_in[0];
    const float* ctx    = (const float*)d_in[1];
    const float* W      = (const float*)d_in[2];
    const float* bias   = (const float*)d_in[3];
    const float* protos = (const float*)d_in[4];
    float* out = (float*)d_out;

    char* ws = (char*)d_ws;
    unsigned char* best = (unsigned char*)ws;                         // 8 MiB
    unsigned short* Xb = (unsigned short*)(ws + ((size_t)9 << 20));   // 16 MiB
    unsigned short* Wb = (unsigned short*)(ws + ((size_t)25 << 20));  // 16 MiB

    hipFuncSetAttribute((const void*)gemm_gather_kernel,
                        hipFuncAttributeMaxDynamicSharedMemorySize, 131072);

    mega_kernel<<<dim3(12288), dim3(256), 0, stream>>>(X, W, Xb, Wb, ctx, protos, best);
    fixup_kernel<<<dim3(1024), dim3(256), 0, stream>>>(ctx, protos, best);
    gemm_gather_kernel<<<dim3(1024), dim3(512), 131072, stream>>>(Xb, Wb, bias, best, out);
}

// Round 17
// 225.356 us; speedup vs baseline: 1.2554x; 1.1702x over previous
//
#include <hip/hip_runtime.h>
#include <hip/hip_bf16.h>

#define N_ 8192
#define I_ 1024
#define O_ 1024
#define P_ 8
#define C_ 64
#define OP_ (O_ * P_)

typedef float f32x4 __attribute__((ext_vector_type(4)));
typedef __bf16 bf16x8 __attribute__((ext_vector_type(8)));
typedef unsigned short ushort4v __attribute__((ext_vector_type(4)));
typedef unsigned short ushort8 __attribute__((ext_vector_type(8)));

#define GLOBAL_AS(p) ((const __attribute__((address_space(1))) unsigned int*)(p))
#define LDS_AS(p) ((__attribute__((address_space(3))) unsigned int*)(p))

// ---------------------------------------------------------------------------
// Kernel M: MEGA — converts + argmin interleaved (r13-r16), argmin role now
// stages the SHARED proto tile once per block (4x dedup of loads + split
// VALU across waves): coop load 32KB fp32 -> in-reg split -> LDS bf16
// [128][72] (144B stride: 16B-aligned b128 reads, 2-way-free banks), psq
// folded into the loader (psqL[128]). Ah/Al values and MFMA order are
// bitwise identical to r16. Flag thr 4e-3 (covers split 2.4e-3 + psq 1e-5).
//   bid%3==2 -> argmin block ; else -> convert block (r14 layouts).
// ---------------------------------------------------------------------------
__global__ __launch_bounds__(256, 2)
void mega_kernel(const float* __restrict__ X, const float* __restrict__ W,
                 unsigned short* __restrict__ Xb, unsigned short* __restrict__ Wb,
                 const float* __restrict__ ctx, const float* __restrict__ protos,
                 unsigned char* __restrict__ best) {
    __shared__ unsigned short AhL[128 * 72];
    __shared__ unsigned short AlL[128 * 72];
    __shared__ float psqL[128];

    const int bid = blockIdx.x;
    const int tid = threadIdx.x;

    if (bid % 3 != 2) {
        // ---------------- convert role (r14 half-tile layouts) --------------
        const int cidx = bid - (bid + 1) / 3;        // 0..8191
        const int side = cidx >> 12;                 // 0: X (layout A), 1: W (layout B)
        const float* src = side ? W : X;
        unsigned short* dst = side ? Wb : Xb;
        const int idx = (cidx & 4095) * 256 + tid;   // 1,048,576 chunks
        const int rb = idx >> 15;
        const int r = idx & 32767;
        const int kt = r >> 11;
        const int h = (r >> 10) & 1;
        const int L = r & 1023;
        const int Lr = L >> 3;
        const int j = L & 7;
        const int c = j ^ (Lr & 7);
        int Rl;
        if (side == 0) Rl = (Lr & 63) + ((Lr & 64) << 1) + h * 64;
        else           Rl = ((Lr >> 5) << 6) + h * 32 + (Lr & 31);
        const float* sp = src + (size_t)(rb * 256 + Rl) * I_ + kt * 64 + c * 8;
        const float4 f0 = *(const float4*)(sp);
        const float4 f1 = *(const float4*)(sp + 4);
        const float f[8] = {f0.x, f0.y, f0.z, f0.w, f1.x, f1.y, f1.z, f1.w};
        ushort8 v;
        #pragma unroll
        for (int e = 0; e < 8; ++e)
            v[e] = __builtin_bit_cast(unsigned short, __float2bfloat16(f[e]));
        *(ushort8*)(dst + (size_t)idx * 8) = v;
        return;
    }

    // ---------------- argmin role (shared proto tile in LDS) ----------------
    const int aidx = bid / 3;                        // 0..4095
    const int w = tid >> 6, l = tid & 63;
    const int op0 = (aidx & 63) * 128;
    const int nw = (aidx >> 6) * 128 + w * 32;
    const int lr = l & 15, lk = l >> 4;

    // ---- cooperative proto load + split + psq: thread -> row tid>>1, half tid&1
    {
        const int r2 = tid >> 1;
        const int hh = tid & 1;
        const float* pr = protos + (size_t)(op0 + r2) * C_ + hh * 32;
        float psum = 0.f;
        #pragma unroll
        for (int j = 0; j < 8; ++j) {
            const float4 v4 = *(const float4*)(pr + j * 4);
            const float f[4] = {v4.x, v4.y, v4.z, v4.w};
            ushort4v vh, vl;
            #pragma unroll
            for (int e = 0; e < 4; ++e) {
                const float f1 = f[e];
                const __hip_bfloat16 hb = __float2bfloat16(f1);
                vh[e] = __builtin_bit_cast(unsigned short, hb);
                vl[e] = __builtin_bit_cast(unsigned short, __float2bfloat16(f1 - __bfloat162float(hb)));
                psum = fmaf(f1, f1, psum);
            }
            const int k = hh * 32 + j * 4;
            *(ushort4v*)&AhL[r2 * 72 + k] = vh;
            *(ushort4v*)&AlL[r2 * 72 + k] = vl;
        }
        psum += __shfl_xor(psum, 1, 64);   // partner half-row
        if (hh == 0) psqL[r2] = psum;
    }
    __syncthreads();

    f32x4 acc[8][2];
    #pragma unroll
    for (int of = 0; of < 8; ++of)
        #pragma unroll
        for (int nf = 0; nf < 2; ++nf) acc[of][nf] = (f32x4)(0.f);

    #pragma unroll
    for (int ks = 0; ks < 2; ++ks) {
        const int ko = ks * 32 + lk * 8;
        bf16x8 Ah[8], Al[8], Bh[2], Bl[2];
        #pragma unroll
        for (int of = 0; of < 8; ++of) {
            const int row = of * 16 + lr;
            Ah[of] = *(const bf16x8*)&AhL[row * 72 + ko];
            Al[of] = *(const bf16x8*)&AlL[row * 72 + ko];
        }
        #pragma unroll
        for (int nf = 0; nf < 2; ++nf) {
            const float* cr = ctx + (size_t)(nw + nf * 16 + lr) * C_ + ko;
            const float4 b0 = *(const float4*)(cr);
            const float4 b1 = *(const float4*)(cr + 4);
            const float fb[8] = {b0.x, b0.y, b0.z, b0.w, b1.x, b1.y, b1.z, b1.w};
            #pragma unroll
            for (int e = 0; e < 8; ++e) {
                const float f = fb[e];
                const __hip_bfloat16 hh2 = __float2bfloat16(f);
                Bh[nf][e] = __builtin_bit_cast(__bf16, __builtin_bit_cast(unsigned short, hh2));
                Bl[nf][e] = __builtin_bit_cast(__bf16, __builtin_bit_cast(unsigned short,
                                __float2bfloat16(f - __bfloat162float(hh2))));
            }
        }
        #pragma unroll
        for (int of = 0; of < 8; ++of)
            #pragma unroll
            for (int nf = 0; nf < 2; ++nf) {
                acc[of][nf] = __builtin_amdgcn_mfma_f32_16x16x32_bf16(Ah[of], Bh[nf], acc[of][nf], 0, 0, 0);
                acc[of][nf] = __builtin_amdgcn_mfma_f32_16x16x32_bf16(Ah[of], Bl[nf], acc[of][nf], 0, 0, 0);
                acc[of][nf] = __builtin_amdgcn_mfma_f32_16x16x32_bf16(Al[of], Bh[nf], acc[of][nf], 0, 0, 0);
            }
    }

    #pragma unroll
    for (int of = 0; of < 8; ++of) {
        const int oprow0 = op0 + of * 16;
        const f32x4 ps = *(const f32x4*)&psqL[of * 16 + lk * 4];
        #pragma unroll
        for (int nf = 0; nf < 2; ++nf) {
            const float d0 = fmaf(-2.f, acc[of][nf][0], ps[0]);
            const float d1 = fmaf(-2.f, acc[of][nf][1], ps[1]);
            const float d2 = fmaf(-2.f, acc[of][nf][2], ps[2]);
            const float d3 = fmaf(-2.f, acc[of][nf][3], ps[3]);
            const float e0 = __shfl_xor(d0, 16, 64);
            const float e1 = __shfl_xor(d1, 16, 64);
            const float e2 = __shfl_xor(d2, 16, 64);
            const float e3 = __shfl_xor(d3, 16, 64);
            float b1v = 3.4e38f, b2v = 3.4e38f;
            int bi = 0;
            #define UPD(val, pidx) do { const float _f = (val);                       \
                if (_f < b1v) { b2v = b1v; b1v = _f; bi = (pidx); }                   \
                else if (_f < b2v) b2v = _f; } while (0)
            UPD(d0, 0); UPD(d1, 1); UPD(d2, 2); UPD(d3, 3);
            UPD(e0, 4); UPD(e1, 5); UPD(e2, 6); UPD(e3, 7);
            #undef UPD
            if ((lk & 1) == 0) {
                const int o = (oprow0 >> 3) + (lk >> 1);
                const int n = nw + nf * 16 + lr;
                const unsigned flag = (b2v - b1v < 4e-3f) ? 0x80u : 0u;
                best[(size_t)o * N_ + n] = (unsigned char)((unsigned)bi | flag);
            }
        }
    }
}

// ---------------------------------------------------------------------------
// Kernel F: block-local fixup (validated r14-r16). LDS queue, 8 lanes/elem
// fp64, ascending-p first-min; clears flag bits.
// ---------------------------------------------------------------------------
__global__ __launch_bounds__(256)
void fixup_kernel(const float* __restrict__ ctx, const float* __restrict__ protos,
                  unsigned char* __restrict__ best) {
    __shared__ unsigned q[8192];
    __shared__ unsigned qcnt;
    const int tid = threadIdx.x;
    if (tid == 0) qcnt = 0;
    __syncthreads();

    const size_t base = (size_t)blockIdx.x * 8192;
    const uint4* bw4 = (const uint4*)(best + base);
    #pragma unroll
    for (int i = 0; i < 2; ++i) {
        const uint4 v = bw4[tid * 2 + i];
        const unsigned wds[4] = {v.x, v.y, v.z, v.w};
        #pragma unroll
        for (int wq = 0; wq < 4; ++wq) {
            unsigned fl = wds[wq] & 0x80808080u;
            while (fl) {
                const int bq = __builtin_ctz(fl) >> 3;
                fl &= fl - 1;
                const unsigned slot = atomicAdd(&qcnt, 1u);
                q[slot] = (unsigned)(tid * 32 + i * 16 + wq * 4 + bq);
            }
        }
    }
    __syncthreads();

    const unsigned cnt = qcnt;
    const int lane8 = tid & 7;
    for (unsigned e = (unsigned)(tid >> 3); e < cnt; e += 32) {
        const size_t off = base + q[e];
        const int n = (int)(off & (N_ - 1));
        const int o = (int)(off >> 13);
        const float* cr = ctx + (size_t)n * C_;
        const float* pr = protos + ((size_t)o * 8 + lane8) * C_;
        double s = 0.0;
        #pragma unroll 8
        for (int c = 0; c < C_; ++c) {
            const double pv = (double)pr[c];
            const double cv = (double)cr[c];
            s += pv * (pv - 2.0 * cv);
        }
        int bi = lane8;
        #pragma unroll
        for (int d = 1; d < 8; d <<= 1) {
            const double s2 = __shfl_xor(s, d, 64);
            const int b2 = __shfl_xor(bi, d, 64);
            if (s2 < s || (s2 == s && b2 < bi)) { s = s2; bi = b2; }
        }
        if (lane8 == 0) best[off] = (unsigned char)bi;
    }
}

// ---------------------------------------------------------------------------
// Kernel B: 256x256 phase-pipelined bf16 MFMA GEMM — r14/r16 VERBATIM
// (151us plateau) + fused argmin-gather epilogue.
// ---------------------------------------------------------------------------
__global__ __launch_bounds__(512, 1)
void gemm_gather_kernel(const unsigned short* __restrict__ Xb,
                        const unsigned short* __restrict__ Wb,
                        const float* __restrict__ bias,
                        const unsigned char* __restrict__ best,
                        float* __restrict__ out) {
    extern __shared__ unsigned short lds[];  // 2 x (A 16384 + B 16384) ushort = 128 KiB

    int wg = blockIdx.x;                     // 1024 blocks, %8==0 -> bijective
    wg = (wg & 7) * 128 + (wg >> 3);
    const int bx = wg & 31;
    const int by = wg >> 5;
    const int n0 = by * 256;
    const int col0 = bx * 256;

    const int tid = threadIdx.x;
    const int w = tid >> 6, l = tid & 63;
    const int wr = w >> 2, wc = w & 3;
    const int lr = l & 15, lk = l >> 4;
    const int lx = lr & 7;

    const unsigned short* Xrb = Xb + (size_t)(n0 >> 8) * 262144;
    const unsigned short* Wrb = Wb + (size_t)(col0 >> 8) * 262144;

    #define STAGE(src, ktt, h, ldsofs) do {                                          \
        const unsigned short* _g = (src) + ((size_t)(ktt) * 2 + (h)) * 8192;         \
        __builtin_amdgcn_global_load_lds(GLOBAL_AS(_g + (size_t)tid * 8),            \
            LDS_AS(lds + (ldsofs) + tid * 8), 16, 0, 0);                             \
        __builtin_amdgcn_global_load_lds(GLOBAL_AS(_g + (size_t)(tid + 512) * 8),    \
            LDS_AS(lds + (ldsofs) + (tid + 512) * 8), 16, 0, 0);                     \
    } while (0)

    #define VMCNT4() do { asm volatile("s_waitcnt vmcnt(4)" ::: "memory");           \
        __builtin_amdgcn_sched_barrier(0); } while (0)
    #define VMCNT2() do { asm volatile("s_waitcnt vmcnt(2)" ::: "memory");           \
        __builtin_amdgcn_sched_barrier(0); } while (0)
    #define VMCNT0() do { asm volatile("s_waitcnt vmcnt(0)" ::: "memory");           \
        __builtin_amdgcn_sched_barrier(0); } while (0)
    #define BAR() __builtin_amdgcn_s_barrier()

    f32x4 acc[8][4];
    #pragma unroll
    for (int m = 0; m < 8; ++m)
        #pragma unroll
        for (int n = 0; n < 4; ++n) acc[m][n] = (f32x4)(0.f);

    #define RD_A(dst, mbase, bb) do {                                                \
        _Pragma("unroll")                                                            \
        for (int _m = 0; _m < 4; ++_m) {                                             \
            const int _R = wr * 128 + ((mbase) + _m) * 16 + lr;                      \
            const int _h = (_R >> 6) & 1;                                            \
            const int _Lr = (_R & 63) + ((_R & 128) >> 1);                           \
            _Pragma("unroll")                                                        \
            for (int _k = 0; _k < 2; ++_k) {                                         \
                const int _s = (_k * 4 + lk) ^ lx;                                   \
                dst[_m][_k] = *(const bf16x8*)&lds[(bb) * 32768 + _h * 8192 +        \
                                                   _Lr * 64 + _s * 8];               \
            }                                                                        \
        }                                                                            \
    } while (0)

    #define RD_B(dst, nbase, bb) do {                                                \
        _Pragma("unroll")                                                            \
        for (int _n = 0; _n < 2; ++_n) {                                             \
            const int _R = wc * 64 + ((nbase) + _n) * 16 + lr;                       \
            const int _h = (_R >> 5) & 1;                                            \
            const int _Lr = ((_R >> 6) << 5) + (_R & 31);                            \
            _Pragma("unroll")                                                        \
            for (int _k = 0; _k < 2; ++_k) {                                         \
                const int _s = (_k * 4 + lk) ^ lx;                                   \
                dst[_n][_k] = *(const bf16x8*)&lds[(bb) * 32768 + 16384 +            \
                                                   _h * 8192 + _Lr * 64 + _s * 8];   \
            }                                                                        \
        }                                                                            \
    } while (0)

    #define MFMA16(AF, BF, MB, NB) do {                                              \
        __builtin_amdgcn_s_setprio(1);                                               \
        _Pragma("unroll")                                                            \
        for (int _m = 0; _m < 4; ++_m)                                               \
            _Pragma("unroll")                                                        \
            for (int _n = 0; _n < 2; ++_n)                                           \
                _Pragma("unroll")                                                    \
                for (int _k = 0; _k < 2; ++_k)                                       \
                    acc[(MB) + _m][(NB) + _n] =                                      \
                        __builtin_amdgcn_mfma_f32_16x16x32_bf16(                     \
                            AF[_m][_k], BF[_n][_k], acc[(MB) + _m][(NB) + _n], 0, 0, 0); \
        __builtin_amdgcn_s_setprio(0);                                               \
    } while (0)

    bf16x8 af[4][2], bfa[2][2], bfb[2][2];

    // ---- prologue: stage kt0 {Aa,Ba,Bb,Ab}; drain Aa0,Ba0 ----
    STAGE(Xrb, 0, 0, 0);
    STAGE(Wrb, 0, 0, 16384);
    STAGE(Wrb, 0, 1, 16384 + 8192);
    STAGE(Xrb, 0, 1, 8192);
    VMCNT4();
    BAR();

    #pragma unroll 1
    for (int kt = 0; kt < 15; ++kt) {
        const int b = kt & 1, nb = b ^ 1;
        const int nbo = nb * 32768;
        RD_A(af, 0, b);
        RD_B(bfa, 0, b);
        STAGE(Wrb, kt + 1, 0, nbo + 16384);
        VMCNT4();
        BAR();
        MFMA16(af, bfa, 0, 0);
        RD_B(bfb, 2, b);
        STAGE(Xrb, kt + 1, 0, nbo);
        VMCNT4();
        BAR();
        MFMA16(af, bfb, 0, 2);
        RD_A(af, 4, b);
        STAGE(Wrb, kt + 1, 1, nbo + 16384 + 8192);
        VMCNT4();
        BAR();
        MFMA16(af, bfb, 4, 2);
        RD_B(bfa, 0, b);
        STAGE(Xrb, kt + 1, 1, nbo + 8192);
        VMCNT4();
        BAR();
        MFMA16(af, bfa, 4, 0);
    }
    {   // tail kt=15 (buf 1, no staging)
        RD_A(af, 0, 1);
        RD_B(bfa, 0, 1);
        VMCNT2();
        BAR();
        MFMA16(af, bfa, 0, 0);
        RD_B(bfb, 2, 1);
        VMCNT0();
        BAR();
        MFMA16(af, bfb, 0, 2);
        RD_A(af, 4, 1);
        MFMA16(af, bfb, 4, 2);
        RD_B(bfa, 0, 1);
        MFMA16(af, bfa, 4, 0);
    }

    // ---- epilogue: fused argmin-gather + bias; u32 best loads ----
    const int nbase = n0 + wr * 128 + lk * 4;
    #pragma unroll
    for (int nf = 0; nf < 4; ++nf) {
        const int opcol = col0 + wc * 64 + nf * 16 + lr;
        const int o = opcol >> 3;
        const unsigned p = (unsigned)(opcol & 7);
        const float bv = bias[opcol];
        const unsigned char* brow = best + (size_t)o * N_ + nbase;
        #pragma unroll
        for (int m = 0; m < 8; ++m) {
            const unsigned b4 = *(const unsigned*)(brow + m * 16);
            #pragma unroll
            for (int j = 0; j < 4; ++j) {
                if (((b4 >> (j * 8)) & 255u) == p) {
                    const int n = nbase + m * 16 + j;
                    out[(size_t)n * O_ + o] = acc[m][nf][j] + bv;
                }
            }
        }
    }
    #undef STAGE
    #undef RD_A
    #undef RD_B
    #undef MFMA16
    #undef VMCNT4
    #undef VMCNT2
    #undef VMCNT0
    #undef BAR
}

// ---------------------------------------------------------------------------
extern "C" void kernel_launch(void* const* d_in, const int* in_sizes, int n_in,
                              void* d_out, int out_size, void* d_ws, size_t ws_size,
                              hipStream_t stream) {
    const float* X      = (const float*)d_in[0];
    const float* ctx    = (const float*)d_in[1];
    const float* W      = (const float*)d_in[2];
    const float* bias   = (const float*)d_in[3];
    const float* protos = (const float*)d_in[4];
    float* out = (float*)d_out;

    char* ws = (char*)d_ws;
    unsigned char* best = (unsigned char*)ws;                         // 8 MiB
    unsigned short* Xb = (unsigned short*)(ws + ((size_t)9 << 20));   // 16 MiB
    unsigned short* Wb = (unsigned short*)(ws + ((size_t)25 << 20));  // 16 MiB

    hipFuncSetAttribute((const void*)gemm_gather_kernel,
                        hipFuncAttributeMaxDynamicSharedMemorySize, 131072);

    mega_kernel<<<dim3(12288), dim3(256), 0, stream>>>(X, W, Xb, Wb, ctx, protos, best);
    fixup_kernel<<<dim3(1024), dim3(256), 0, stream>>>(ctx, protos, best);
    gemm_gather_kernel<<<dim3(1024), dim3(512), 131072, stream>>>(Xb, Wb, bias, best, out);
}